// Round 1
// baseline (844.769 us; speedup 1.0000x reference)
//
#include <hip/hip_runtime.h>
#include <hip/hip_bf16.h>

// RGCN: 2-layer relational GCN + L2 normalize.
// Strategy: aggregate-then-transform (matmul linearity), CSR-based gather
// aggregation (no fp32 atomics), fused 3-segment fp32 GEMM.

#define IN_CH  128
#define HID_CH 128
#define OUT_CH 64
#define SCAN_CHUNK 2048   // 256 threads * 8 elements

// ---------------- CSR build ----------------

__global__ void k_hist(const int* __restrict__ dst, const int* __restrict__ et,
                       int* __restrict__ deg, int E, int N) {
    int e = blockIdx.x * blockDim.x + threadIdx.x;
    if (e < E) atomicAdd(&deg[et[e] * N + dst[e]], 1);
}

__global__ void k_scan_a(const int* __restrict__ deg, int* __restrict__ offs,
                         int* __restrict__ bsums, int n) {
    __shared__ int sdata[256];
    int b = blockIdx.x, t = threadIdx.x;
    int base = b * SCAN_CHUNK + t * 8;
    int v[8];
    int sum = 0;
#pragma unroll
    for (int i = 0; i < 8; i++) {
        int idx = base + i;
        int x = (idx < n) ? deg[idx] : 0;
        v[i] = sum;      // exclusive within-thread prefix
        sum += x;
    }
    sdata[t] = sum;
    __syncthreads();
    // inclusive Hillis-Steele scan over 256 thread sums
    for (int ofs = 1; ofs < 256; ofs <<= 1) {
        int val = sdata[t];
        int add = (t >= ofs) ? sdata[t - ofs] : 0;
        __syncthreads();
        sdata[t] = val + add;
        __syncthreads();
    }
    int texcl = (t == 0) ? 0 : sdata[t - 1];
    if (t == 255) bsums[b] = sdata[255];
#pragma unroll
    for (int i = 0; i < 8; i++) {
        int idx = base + i;
        if (idx < n) offs[idx] = texcl + v[i];
    }
}

__global__ void k_scan_b(int* __restrict__ bsums, int* __restrict__ offs, int nb, int n) {
    if (blockIdx.x == 0 && threadIdx.x == 0) {
        int run = 0;
        for (int b = 0; b < nb; b++) {
            int t = bsums[b];
            bsums[b] = run;
            run += t;
        }
        offs[n] = run;   // total == E
    }
}

__global__ void k_scan_c(int* __restrict__ offs, const int* __restrict__ bsums, int n) {
    int i = blockIdx.x * blockDim.x + threadIdx.x;
    if (i < n) offs[i] += bsums[i / SCAN_CHUNK];
}

__global__ void k_fill(const int* __restrict__ src, const int* __restrict__ dst,
                       const int* __restrict__ et, const int* __restrict__ offs,
                       int* __restrict__ cursor, int* __restrict__ esrc, int E, int N) {
    int e = blockIdx.x * blockDim.x + threadIdx.x;
    if (e < E) {
        int key = et[e] * N + dst[e];
        int pos = offs[key] + atomicAdd(&cursor[key], 1);
        esrc[pos] = src[e];
    }
}

// ---------------- per-(rel,node) neighbor mean: gather based ----------------
// One wave (64 lanes) per segment; lane handles 2 channels (float2) -> one
// coalesced 512B row read per edge. Writes every segment (zero if empty), so
// the S buffer never needs pre-zeroing.

__global__ void k_agg(const float* __restrict__ feat, const int* __restrict__ offs,
                      const int* __restrict__ esrc, float* __restrict__ S, int nseg) {
    int wid = (int)((blockIdx.x * (long long)blockDim.x + threadIdx.x) >> 6);
    int lane = threadIdx.x & 63;
    if (wid >= nseg) return;
    int beg = offs[wid], end = offs[wid + 1];
    float2 acc = make_float2(0.f, 0.f);
    for (int e = beg; e < end; e++) {
        int s = esrc[e];
        const float2* row = (const float2*)(feat + (size_t)s * IN_CH);
        float2 r = row[lane];
        acc.x += r.x;
        acc.y += r.y;
    }
    float inv = 1.0f / fmaxf((float)(end - beg), 1.0f);
    float2* o = (float2*)(S + (size_t)wid * IN_CH);
    o[lane] = make_float2(acc.x * inv, acc.y * inv);
}

// ---------------- fused 3-segment GEMM ----------------
// out[n][j] = opt_relu( bias[j] + sum_seg A_seg[n,:] . W_seg[:,j] )
// A_seg: [N x 128] row-major. W_seg: [128 x Cout] row-major.
// Block: 256 threads, BM=64 x BN=64 tile, 4x4 microtile, BK=16 LDS stages.

#define BM 64
#define BN 64
#define BK 16

__global__ __launch_bounds__(256)
void k_gemm3(const float* __restrict__ A0, const float* __restrict__ A1,
             const float* __restrict__ A2,
             const float* __restrict__ W0, const float* __restrict__ W1,
             const float* __restrict__ W2,
             const float* __restrict__ bias, float* __restrict__ out,
             int N, int Cout, int do_relu) {
    __shared__ float As[BK][BM + 4];   // stride 68 floats: 16B-aligned rows
    __shared__ float Ws[BK][BN + 4];

    int tid = threadIdx.x;
    int tm = tid >> 4;      // 0..15 -> 4-row group
    int tn = tid & 15;      // 0..15 -> 4-col group
    int rowBase = blockIdx.x * BM;
    int colBase = blockIdx.y * BN;

    float acc[4][4] = {};

    const float* Aseg[3] = {A0, A1, A2};
    const float* Wseg[3] = {W0, W1, W2};

    for (int seg = 0; seg < 3; seg++) {
        const float* A = Aseg[seg];
        const float* W = Wseg[seg];
        for (int k0 = 0; k0 < 128; k0 += BK) {
            // Stage A chunk: 64 rows x 16 k. Each thread: one float4.
            {
                int row = tid >> 2;        // 0..63
                int kq = tid & 3;          // 0..3 -> k = kq*4
                int gr = rowBase + row;
                if (gr >= N) gr = N - 1;   // clamp (stores masked later)
                const float4 av = *(const float4*)(A + (size_t)gr * 128 + k0 + kq * 4);
                As[kq * 4 + 0][row] = av.x;
                As[kq * 4 + 1][row] = av.y;
                As[kq * 4 + 2][row] = av.z;
                As[kq * 4 + 3][row] = av.w;
            }
            // Stage W chunk: 16 k x 64 cols. Each thread: one float4.
            {
                int kr = tid >> 4;         // 0..15
                int jq = tid & 15;         // 0..15 -> col = jq*4
                float4 wv = *(const float4*)(W + (size_t)(k0 + kr) * Cout + colBase + jq * 4);
                *(float4*)&Ws[kr][jq * 4] = wv;
            }
            __syncthreads();
#pragma unroll
            for (int kk = 0; kk < BK; kk++) {
                float4 a = *(const float4*)&As[kk][tm * 4];
                float4 w = *(const float4*)&Ws[kk][tn * 4];
                float av[4] = {a.x, a.y, a.z, a.w};
                float wv[4] = {w.x, w.y, w.z, w.w};
#pragma unroll
                for (int i = 0; i < 4; i++)
#pragma unroll
                    for (int j = 0; j < 4; j++)
                        acc[i][j] += av[i] * wv[j];
            }
            __syncthreads();
        }
    }

    // Epilogue: bias (+relu), masked float4 store.
    float4 bv = *(const float4*)(bias + colBase + tn * 4);
    float bb[4] = {bv.x, bv.y, bv.z, bv.w};
#pragma unroll
    for (int i = 0; i < 4; i++) {
        int gr = rowBase + tm * 4 + i;
        if (gr < N) {
            float4 r;
            float t0 = acc[i][0] + bb[0];
            float t1 = acc[i][1] + bb[1];
            float t2 = acc[i][2] + bb[2];
            float t3 = acc[i][3] + bb[3];
            if (do_relu) {
                t0 = fmaxf(t0, 0.f); t1 = fmaxf(t1, 0.f);
                t2 = fmaxf(t2, 0.f); t3 = fmaxf(t3, 0.f);
            }
            r.x = t0; r.y = t1; r.z = t2; r.w = t3;
            *(float4*)(out + (size_t)gr * Cout + colBase + tn * 4) = r;
        }
    }
}

// ---------------- L2 normalize rows of [N x 64] ----------------

__global__ void k_l2norm(float* __restrict__ out, int N) {
    int gid = blockIdx.x * blockDim.x + threadIdx.x;
    int row = gid >> 6;
    int lane = threadIdx.x & 63;
    if (row >= N) return;
    float v = out[(size_t)row * OUT_CH + lane];
    float sq = v * v;
#pragma unroll
    for (int o = 1; o < 64; o <<= 1) sq += __shfl_xor(sq, o, 64);
    float nrm = sqrtf(sq);
    out[(size_t)row * OUT_CH + lane] = v / fmaxf(nrm, 1e-12f);
}

// ---------------- launch ----------------

extern "C" void kernel_launch(void* const* d_in, const int* in_sizes, int n_in,
                              void* d_out, int out_size, void* d_ws, size_t ws_size,
                              hipStream_t stream) {
    const float* x      = (const float*)d_in[0];
    const int*   ei     = (const int*)d_in[1];
    const int*   etype  = (const int*)d_in[2];
    const float* W1rel  = (const float*)d_in[3];  // [2,128,128]
    const float* W1root = (const float*)d_in[4];  // [128,128]
    const float* b1     = (const float*)d_in[5];
    const float* W2rel  = (const float*)d_in[6];  // [2,128,64]
    const float* W2root = (const float*)d_in[7];  // [128,64]
    const float* b2     = (const float*)d_in[8];
    float* out = (float*)d_out;

    const int N = in_sizes[0] / IN_CH;   // 100000
    const int E = in_sizes[2];           // 1600000
    const int NSEG = 2 * N;              // rel-major segments: key = r*N + dst

    const int* src = ei;
    const int* dst = ei + E;

    // workspace carve-up (aligned to 512B)
    char* base = (char*)d_ws;
    size_t off = 0;
    auto carve = [&](size_t bytes) -> void* {
        void* p = base + off;
        off = (off + bytes + 511) & ~(size_t)511;
        return p;
    };
    float* S      = (float*)carve((size_t)NSEG * IN_CH * sizeof(float));  // 102.4 MB
    float* h      = (float*)carve((size_t)N * HID_CH * sizeof(float));    // 51.2 MB
    int*   esrc   = (int*)carve((size_t)E * sizeof(int));                 // 6.4 MB
    int*   deg    = (int*)carve((size_t)NSEG * sizeof(int));
    int*   offs   = (int*)carve((size_t)(NSEG + 1) * sizeof(int));
    int*   cursor = (int*)carve((size_t)NSEG * sizeof(int));
    int    NB     = (NSEG + SCAN_CHUNK - 1) / SCAN_CHUNK;
    int*   bsums  = (int*)carve((size_t)NB * sizeof(int));
    (void)ws_size; (void)n_in; (void)out_size;

    hipMemsetAsync(deg, 0, (size_t)NSEG * sizeof(int), stream);
    hipMemsetAsync(cursor, 0, (size_t)NSEG * sizeof(int), stream);

    int eb = (E + 255) / 256;
    k_hist<<<eb, 256, 0, stream>>>(dst, etype, deg, E, N);
    k_scan_a<<<NB, 256, 0, stream>>>(deg, offs, bsums, NSEG);
    k_scan_b<<<1, 64, 0, stream>>>(bsums, offs, NB, NSEG);
    k_scan_c<<<(NSEG + 255) / 256, 256, 0, stream>>>(offs, bsums, NSEG);
    k_fill<<<eb, 256, 0, stream>>>(src, dst, etype, offs, cursor, esrc, E, N);

    int aggBlocks = (int)(((long long)NSEG * 64 + 255) / 256);
    int rowTiles = (N + BM - 1) / BM;

    // Layer 1
    k_agg<<<aggBlocks, 256, 0, stream>>>(x, offs, esrc, S, NSEG);
    k_gemm3<<<dim3(rowTiles, HID_CH / BN), 256, 0, stream>>>(
        x, S, S + (size_t)N * IN_CH,
        W1root, W1rel, W1rel + 128 * 128,
        b1, h, N, HID_CH, 1);

    // Layer 2
    k_agg<<<aggBlocks, 256, 0, stream>>>(h, offs, esrc, S, NSEG);
    k_gemm3<<<dim3(rowTiles, OUT_CH / BN), 256, 0, stream>>>(
        h, S, S + (size_t)N * IN_CH,
        W2root, W2rel, W2rel + 128 * 64,
        b2, out, N, OUT_CH, 0);

    // L2 normalize
    k_l2norm<<<(int)(((long long)N * 64 + 255) / 256), 256, 0, stream>>>(out, N);
}

// Round 2
// 719.451 us; speedup vs baseline: 1.1742x; 1.1742x over previous
//
#include <hip/hip_runtime.h>
#include <hip/hip_bf16.h>

// RGCN: 2-layer relational GCN + L2 normalize.
// R1: layer-2 transform-then-aggregate + fused epilogue; unrolled gathers;
//     8x4-microtile fp32 GEMM; cursor-free CSR fill.

#define IN_CH  128
#define HID_CH 128
#define OUT_CH 64
#define SCAN_CHUNK 2048   // 256 threads * 8 elements

// ---------------- CSR build ----------------

__global__ void k_hist(const int* __restrict__ dst, const int* __restrict__ et,
                       int* __restrict__ deg, int E, int N) {
    int e = blockIdx.x * blockDim.x + threadIdx.x;
    if (e < E) atomicAdd(&deg[et[e] * N + dst[e]], 1);
}

__global__ void k_scan_a(const int* __restrict__ deg, int* __restrict__ offs,
                         int* __restrict__ bsums, int n) {
    __shared__ int sdata[256];
    int b = blockIdx.x, t = threadIdx.x;
    int base = b * SCAN_CHUNK + t * 8;
    int v[8];
    int sum = 0;
#pragma unroll
    for (int i = 0; i < 8; i++) {
        int idx = base + i;
        int x = (idx < n) ? deg[idx] : 0;
        v[i] = sum;
        sum += x;
    }
    sdata[t] = sum;
    __syncthreads();
    for (int ofs = 1; ofs < 256; ofs <<= 1) {
        int val = sdata[t];
        int add = (t >= ofs) ? sdata[t - ofs] : 0;
        __syncthreads();
        sdata[t] = val + add;
        __syncthreads();
    }
    int texcl = (t == 0) ? 0 : sdata[t - 1];
    if (t == 255) bsums[b] = sdata[255];
#pragma unroll
    for (int i = 0; i < 8; i++) {
        int idx = base + i;
        if (idx < n) offs[idx] = texcl + v[i];
    }
}

__global__ void k_scan_b(int* __restrict__ bsums, int* __restrict__ offs, int nb, int n) {
    if (blockIdx.x == 0 && threadIdx.x == 0) {
        int run = 0;
        for (int b = 0; b < nb; b++) {
            int t = bsums[b];
            bsums[b] = run;
            run += t;
        }
        offs[n] = run;
    }
}

__global__ void k_scan_c(int* __restrict__ offs, const int* __restrict__ bsums, int n) {
    int i = blockIdx.x * blockDim.x + threadIdx.x;
    if (i < n) offs[i] += bsums[i / SCAN_CHUNK];
}

// Post-increments offs[key] directly: after this kernel, segment k occupies
// [ (k==0 ? 0 : offs[k-1]), offs[k] ).
__global__ void k_fill(const int* __restrict__ src, const int* __restrict__ dst,
                       const int* __restrict__ et, int* __restrict__ offs,
                       int* __restrict__ esrc, int E, int N) {
    int e = blockIdx.x * blockDim.x + threadIdx.x;
    if (e < E) {
        int key = et[e] * N + dst[e];
        int pos = atomicAdd(&offs[key], 1);
        esrc[pos] = src[e];
    }
}

// ---------------- layer-1 neighbor mean (gather, unrolled x4) --------------
// One wave per (rel,node) segment; lane handles 2 channels (float2).

__global__ void k_agg(const float* __restrict__ feat, const int* __restrict__ offs,
                      const int* __restrict__ esrc, float* __restrict__ S, int nseg) {
    int wid = (int)((blockIdx.x * (long long)blockDim.x + threadIdx.x) >> 6);
    int lane = threadIdx.x & 63;
    if (wid >= nseg) return;
    int beg = (wid == 0) ? 0 : offs[wid - 1];
    int end = offs[wid];
    float2 acc = make_float2(0.f, 0.f);
    int e = beg;
    for (; e + 4 <= end; e += 4) {
        int s0 = esrc[e + 0], s1 = esrc[e + 1], s2 = esrc[e + 2], s3 = esrc[e + 3];
        float2 r0 = ((const float2*)(feat + (size_t)s0 * IN_CH))[lane];
        float2 r1 = ((const float2*)(feat + (size_t)s1 * IN_CH))[lane];
        float2 r2 = ((const float2*)(feat + (size_t)s2 * IN_CH))[lane];
        float2 r3 = ((const float2*)(feat + (size_t)s3 * IN_CH))[lane];
        acc.x += r0.x + r1.x + r2.x + r3.x;
        acc.y += r0.y + r1.y + r2.y + r3.y;
    }
    for (; e < end; e++) {
        int s = esrc[e];
        float2 r = ((const float2*)(feat + (size_t)s * IN_CH))[lane];
        acc.x += r.x;
        acc.y += r.y;
    }
    float inv = 1.0f / fmaxf((float)(end - beg), 1.0f);
    ((float2*)(S + (size_t)wid * IN_CH))[lane] = make_float2(acc.x * inv, acc.y * inv);
}

// ---------------- fused 3-segment GEMM (layer 1) ----------------
// h[n][j] = relu( b[j] + sum_seg A_seg[n,:] . W_seg[:,j] ), K=128 per segment.
// Block 256 threads, BM=128 x BN=64, 8x4 microtile, BK=16 stages.

#define BM 128
#define BN 64
#define BK 16

__global__ __launch_bounds__(256)
void k_gemm3(const float* __restrict__ A0, const float* __restrict__ A1,
             const float* __restrict__ A2,
             const float* __restrict__ W0, const float* __restrict__ W1,
             const float* __restrict__ W2,
             const float* __restrict__ bias, float* __restrict__ out,
             int N, int Cout, int do_relu) {
    __shared__ float As[BK][BM + 4];
    __shared__ float Ws[BK][BN + 4];

    int tid = threadIdx.x;
    int tm = tid >> 4;      // 0..15 -> 8-row group
    int tn = tid & 15;      // 0..15 -> 4-col group
    int rowBase = blockIdx.x * BM;
    int colBase = blockIdx.y * BN;

    float acc[8][4] = {};

    const float* Aseg[3] = {A0, A1, A2};
    const float* Wseg[3] = {W0, W1, W2};

    for (int seg = 0; seg < 3; seg++) {
        const float* A = Aseg[seg];
        const float* W = Wseg[seg];
        for (int k0 = 0; k0 < 128; k0 += BK) {
            // Stage A: 128 rows x 16 k = 512 float4; 2 per thread.
#pragma unroll
            for (int it = 0; it < 2; it++) {
                int idx = tid + it * 256;
                int row = idx >> 2;     // 0..127
                int kq = idx & 3;
                int gr = rowBase + row;
                if (gr >= N) gr = N - 1;
                const float4 av = *(const float4*)(A + (size_t)gr * 128 + k0 + kq * 4);
                As[kq * 4 + 0][row] = av.x;
                As[kq * 4 + 1][row] = av.y;
                As[kq * 4 + 2][row] = av.z;
                As[kq * 4 + 3][row] = av.w;
            }
            // Stage W: 16 k x 64 cols = 256 float4; 1 per thread.
            {
                int kr = tid >> 4;
                int jq = tid & 15;
                float4 wv = *(const float4*)(W + (size_t)(k0 + kr) * Cout + colBase + jq * 4);
                *(float4*)&Ws[kr][jq * 4] = wv;
            }
            __syncthreads();
#pragma unroll
            for (int kk = 0; kk < BK; kk++) {
                float4 a0 = *(const float4*)&As[kk][tm * 8];
                float4 a1 = *(const float4*)&As[kk][tm * 8 + 4];
                float4 w = *(const float4*)&Ws[kk][tn * 4];
                float av[8] = {a0.x, a0.y, a0.z, a0.w, a1.x, a1.y, a1.z, a1.w};
                float wv[4] = {w.x, w.y, w.z, w.w};
#pragma unroll
                for (int i = 0; i < 8; i++)
#pragma unroll
                    for (int j = 0; j < 4; j++)
                        acc[i][j] += av[i] * wv[j];
            }
            __syncthreads();
        }
    }

    float4 bv = *(const float4*)(bias + colBase + tn * 4);
    float bb[4] = {bv.x, bv.y, bv.z, bv.w};
#pragma unroll
    for (int i = 0; i < 8; i++) {
        int gr = rowBase + tm * 8 + i;
        if (gr < N) {
            float t0 = acc[i][0] + bb[0];
            float t1 = acc[i][1] + bb[1];
            float t2 = acc[i][2] + bb[2];
            float t3 = acc[i][3] + bb[3];
            if (do_relu) {
                t0 = fmaxf(t0, 0.f); t1 = fmaxf(t1, 0.f);
                t2 = fmaxf(t2, 0.f); t3 = fmaxf(t3, 0.f);
            }
            float4 r = {t0, t1, t2, t3};
            *(float4*)(out + (size_t)gr * Cout + colBase + tn * 4) = r;
        }
    }
}

// ---------------- layer-2 GEMM: t = h @ [W2root | W2rel0 | W2rel1] ---------
// A: [N x 128], each W seg: [128 x 64] (ld 64), out: [N x 192] (ld 192).
// bias added only to seg 0 columns.

__global__ __launch_bounds__(256)
void k_gemmW(const float* __restrict__ A,
             const float* __restrict__ W0, const float* __restrict__ W1,
             const float* __restrict__ W2,
             const float* __restrict__ bias, float* __restrict__ out, int N) {
    __shared__ float As[BK][BM + 4];
    __shared__ float Ws[BK][BN + 4];

    int tid = threadIdx.x;
    int tm = tid >> 4;
    int tn = tid & 15;
    int rowBase = blockIdx.x * BM;
    int seg = blockIdx.y;           // 0..2
    const float* Wseg[3] = {W0, W1, W2};
    const float* W = Wseg[seg];

    float acc[8][4] = {};

    for (int k0 = 0; k0 < 128; k0 += BK) {
#pragma unroll
        for (int it = 0; it < 2; it++) {
            int idx = tid + it * 256;
            int row = idx >> 2;
            int kq = idx & 3;
            int gr = rowBase + row;
            if (gr >= N) gr = N - 1;
            const float4 av = *(const float4*)(A + (size_t)gr * 128 + k0 + kq * 4);
            As[kq * 4 + 0][row] = av.x;
            As[kq * 4 + 1][row] = av.y;
            As[kq * 4 + 2][row] = av.z;
            As[kq * 4 + 3][row] = av.w;
        }
        {
            int kr = tid >> 4;
            int jq = tid & 15;
            float4 wv = *(const float4*)(W + (size_t)(k0 + kr) * 64 + jq * 4);
            *(float4*)&Ws[kr][jq * 4] = wv;
        }
        __syncthreads();
#pragma unroll
        for (int kk = 0; kk < BK; kk++) {
            float4 a0 = *(const float4*)&As[kk][tm * 8];
            float4 a1 = *(const float4*)&As[kk][tm * 8 + 4];
            float4 w = *(const float4*)&Ws[kk][tn * 4];
            float av[8] = {a0.x, a0.y, a0.z, a0.w, a1.x, a1.y, a1.z, a1.w};
            float wv[4] = {w.x, w.y, w.z, w.w};
#pragma unroll
            for (int i = 0; i < 8; i++)
#pragma unroll
                for (int j = 0; j < 4; j++)
                    acc[i][j] += av[i] * wv[j];
        }
        __syncthreads();
    }

    float bb[4] = {0.f, 0.f, 0.f, 0.f};
    if (seg == 0) {
        float4 bv = *(const float4*)(bias + tn * 4);
        bb[0] = bv.x; bb[1] = bv.y; bb[2] = bv.z; bb[3] = bv.w;
    }
#pragma unroll
    for (int i = 0; i < 8; i++) {
        int gr = rowBase + tm * 8 + i;
        if (gr < N) {
            float4 r = {acc[i][0] + bb[0], acc[i][1] + bb[1],
                        acc[i][2] + bb[2], acc[i][3] + bb[3]};
            *(float4*)(out + (size_t)gr * 192 + seg * 64 + tn * 4) = r;
        }
    }
}

// ------------- fused layer-2 aggregate + combine + L2 normalize ------------
// One wave per node; lane = output channel. t: [N x 192]:
//   cols 0..63  = root term (+bias), 64..127 = y0 = h@W2rel0, 128..191 = y1.

__global__ void k_final(const float* __restrict__ t, const int* __restrict__ offs,
                        const int* __restrict__ esrc, float* __restrict__ out, int N) {
    int wid = (int)((blockIdx.x * (long long)blockDim.x + threadIdx.x) >> 6);
    int lane = threadIdx.x & 63;
    if (wid >= N) return;

    float v = t[(size_t)wid * 192 + lane];   // root + bias

#pragma unroll
    for (int r = 0; r < 2; r++) {
        int segk = r * N + wid;
        int beg = (segk == 0) ? 0 : offs[segk - 1];
        int end = offs[segk];
        const float* y = t + 64 + r * 64;
        float acc = 0.f;
        int e = beg;
        for (; e + 4 <= end; e += 4) {
            int s0 = esrc[e + 0], s1 = esrc[e + 1], s2 = esrc[e + 2], s3 = esrc[e + 3];
            float r0 = y[(size_t)s0 * 192 + lane];
            float r1 = y[(size_t)s1 * 192 + lane];
            float r2 = y[(size_t)s2 * 192 + lane];
            float r3 = y[(size_t)s3 * 192 + lane];
            acc += r0 + r1 + r2 + r3;
        }
        for (; e < end; e++) acc += y[(size_t)esrc[e] * 192 + lane];
        v += acc / fmaxf((float)(end - beg), 1.0f);
    }

    float sq = v * v;
#pragma unroll
    for (int o = 1; o < 64; o <<= 1) sq += __shfl_xor(sq, o, 64);
    float nrm = sqrtf(sq);
    out[(size_t)wid * OUT_CH + lane] = v / fmaxf(nrm, 1e-12f);
}

// ---------------- launch ----------------

extern "C" void kernel_launch(void* const* d_in, const int* in_sizes, int n_in,
                              void* d_out, int out_size, void* d_ws, size_t ws_size,
                              hipStream_t stream) {
    const float* x      = (const float*)d_in[0];
    const int*   ei     = (const int*)d_in[1];
    const int*   etype  = (const int*)d_in[2];
    const float* W1rel  = (const float*)d_in[3];  // [2,128,128]
    const float* W1root = (const float*)d_in[4];  // [128,128]
    const float* b1     = (const float*)d_in[5];
    const float* W2rel  = (const float*)d_in[6];  // [2,128,64]
    const float* W2root = (const float*)d_in[7];  // [128,64]
    const float* b2     = (const float*)d_in[8];
    float* out = (float*)d_out;

    const int N = in_sizes[0] / IN_CH;   // 100000
    const int E = in_sizes[2];           // 1600000
    const int NSEG = 2 * N;

    const int* src = ei;
    const int* dst = ei + E;

    char* base = (char*)d_ws;
    size_t off = 0;
    auto carve = [&](size_t bytes) -> void* {
        void* p = base + off;
        off = (off + bytes + 511) & ~(size_t)511;
        return p;
    };
    float* S    = (float*)carve((size_t)NSEG * IN_CH * sizeof(float));  // 102.4 MB
    float* h    = (float*)carve((size_t)N * HID_CH * sizeof(float));    // 51.2 MB
    int*   esrc = (int*)carve((size_t)E * sizeof(int));                 // 6.4 MB
    int*   deg  = (int*)carve((size_t)NSEG * sizeof(int));
    int*   offs = (int*)carve((size_t)(NSEG + 1) * sizeof(int));
    int    NB   = (NSEG + SCAN_CHUNK - 1) / SCAN_CHUNK;
    int*   bsums = (int*)carve((size_t)NB * sizeof(int));
    float* t    = S;   // reuse: S dead after GEMM1; t is N*192 floats (76.8 MB)
    (void)ws_size; (void)n_in; (void)out_size;

    hipMemsetAsync(deg, 0, (size_t)NSEG * sizeof(int), stream);

    int eb = (E + 255) / 256;
    k_hist<<<eb, 256, 0, stream>>>(dst, etype, deg, E, N);
    k_scan_a<<<NB, 256, 0, stream>>>(deg, offs, bsums, NSEG);
    k_scan_b<<<1, 64, 0, stream>>>(bsums, offs, NB, NSEG);
    k_scan_c<<<(NSEG + 255) / 256, 256, 0, stream>>>(offs, bsums, NSEG);
    k_fill<<<eb, 256, 0, stream>>>(src, dst, etype, offs, esrc, E, N);

    int aggBlocks = (int)(((long long)NSEG * 64 + 255) / 256);
    int rowTiles = (N + BM - 1) / BM;

    // Layer 1: aggregate-then-transform.
    k_agg<<<aggBlocks, 256, 0, stream>>>(x, offs, esrc, S, NSEG);
    k_gemm3<<<dim3(rowTiles, HID_CH / BN), 256, 0, stream>>>(
        x, S, S + (size_t)N * IN_CH,
        W1root, W1rel, W1rel + 128 * 128,
        b1, h, N, HID_CH, 1);

    // Layer 2: transform-then-aggregate.
    k_gemmW<<<dim3(rowTiles, 3), 256, 0, stream>>>(
        h, W2root, W2rel, W2rel + 128 * 64, b2, t, N);
    k_final<<<(int)(((long long)N * 64 + 255) / 256), 256, 0, stream>>>(
        t, offs, esrc, out, N);
}

// Round 3
// 539.798 us; speedup vs baseline: 1.5650x; 1.3328x over previous
//
#include <hip/hip_runtime.h>
#include <hip/hip_bf16.h>

// RGCN: 2-layer relational GCN + L2 normalize.
// R2: both layers transform-then-aggregate; bf16 MFMA GEMMs (32x32x16);
//     bf16 message buffers halve gather traffic; frag-ordered LDS staging.

typedef unsigned int uint;
typedef unsigned short ushort;
typedef __attribute__((ext_vector_type(8))) short short8;
typedef __attribute__((ext_vector_type(16))) float floatx16;

#define IN_CH  128
#define OUT_CH 64
#define SCAN_CHUNK 2048

__device__ __forceinline__ ushort f2bf(float f) {
    uint u = __float_as_uint(f);
    u += 0x7FFF + ((u >> 16) & 1);          // round-to-nearest-even
    return (ushort)(u >> 16);
}
__device__ __forceinline__ float bflo(uint u) { return __uint_as_float(u << 16); }
__device__ __forceinline__ float bfhi(uint u) { return __uint_as_float(u & 0xFFFF0000u); }
__device__ __forceinline__ float bf1(ushort s) { return __uint_as_float(((uint)s) << 16); }

// ---------------- CSR build (unchanged from R1) ----------------

__global__ void k_hist(const int* __restrict__ dst, const int* __restrict__ et,
                       int* __restrict__ deg, int E, int N) {
    int e = blockIdx.x * blockDim.x + threadIdx.x;
    if (e < E) atomicAdd(&deg[et[e] * N + dst[e]], 1);
}

__global__ void k_scan_a(const int* __restrict__ deg, int* __restrict__ offs,
                         int* __restrict__ bsums, int n) {
    __shared__ int sdata[256];
    int b = blockIdx.x, t = threadIdx.x;
    int base = b * SCAN_CHUNK + t * 8;
    int v[8];
    int sum = 0;
#pragma unroll
    for (int i = 0; i < 8; i++) {
        int idx = base + i;
        int x = (idx < n) ? deg[idx] : 0;
        v[i] = sum;
        sum += x;
    }
    sdata[t] = sum;
    __syncthreads();
    for (int ofs = 1; ofs < 256; ofs <<= 1) {
        int val = sdata[t];
        int add = (t >= ofs) ? sdata[t - ofs] : 0;
        __syncthreads();
        sdata[t] = val + add;
        __syncthreads();
    }
    int texcl = (t == 0) ? 0 : sdata[t - 1];
    if (t == 255) bsums[b] = sdata[255];
#pragma unroll
    for (int i = 0; i < 8; i++) {
        int idx = base + i;
        if (idx < n) offs[idx] = texcl + v[i];
    }
}

__global__ void k_scan_b(int* __restrict__ bsums, int* __restrict__ offs, int nb, int n) {
    if (blockIdx.x == 0 && threadIdx.x == 0) {
        int run = 0;
        for (int b = 0; b < nb; b++) {
            int t = bsums[b];
            bsums[b] = run;
            run += t;
        }
        offs[n] = run;
    }
}

__global__ void k_scan_c(int* __restrict__ offs, const int* __restrict__ bsums, int n) {
    int i = blockIdx.x * blockDim.x + threadIdx.x;
    if (i < n) offs[i] += bsums[i / SCAN_CHUNK];
}

// After k_fill: segment k occupies [ (k==0 ? 0 : offs[k-1]), offs[k] ).
__global__ void k_fill(const int* __restrict__ src, const int* __restrict__ dst,
                       const int* __restrict__ et, int* __restrict__ offs,
                       int* __restrict__ esrc, int E, int N) {
    int e = blockIdx.x * blockDim.x + threadIdx.x;
    if (e < E) {
        int key = et[e] * N + dst[e];
        int pos = atomicAdd(&offs[key], 1);
        esrc[pos] = src[e];
    }
}

// ---------------- fp32 -> bf16 conversion of x ----------------

__global__ void k_cvt(const float* __restrict__ x, uint4* __restrict__ xb, int n8) {
    int i = blockIdx.x * 256 + threadIdx.x;
    if (i >= n8) return;
    const float4 f0 = ((const float4*)x)[(size_t)i * 2];
    const float4 f1 = ((const float4*)x)[(size_t)i * 2 + 1];
    uint4 o;
    o.x = (uint)f2bf(f0.x) | ((uint)f2bf(f0.y) << 16);
    o.y = (uint)f2bf(f0.z) | ((uint)f2bf(f0.w) << 16);
    o.z = (uint)f2bf(f1.x) | ((uint)f2bf(f1.y) << 16);
    o.w = (uint)f2bf(f1.z) | ((uint)f2bf(f1.w) << 16);
    xb[i] = o;
}

// ------------- weight pre-pack into MFMA-B fragment order (bf16) -----------
// Per 128-col tile: chunk c = gn*512 + s*64 + h*32 + n holds
// B[k = s*16+h*8+j][col = gn*32+n], j=0..7  (16B). Tile = 2048 chunks = 32KB.
// Bpk1: 3 tiles for [W1root|W1rel0|W1rel1]; Bpk2: 2 tiles for
// [W2root|W2rel0|W2rel1|zeros] (cols 192..255 zero-padded).

__device__ __forceinline__ uint4 pack8(const ushort* o) {
    uint4 v;
    v.x = (uint)o[0] | ((uint)o[1] << 16);
    v.y = (uint)o[2] | ((uint)o[3] << 16);
    v.z = (uint)o[4] | ((uint)o[5] << 16);
    v.w = (uint)o[6] | ((uint)o[7] << 16);
    return v;
}

__global__ void k_prep(const float* __restrict__ W1root, const float* __restrict__ W1rel,
                       const float* __restrict__ W2root, const float* __restrict__ W2rel,
                       uint4* __restrict__ Bpk1, uint4* __restrict__ Bpk2) {
    int idx = blockIdx.x * 256 + threadIdx.x;
    if (idx >= 10240) return;
    ushort o[8];
    if (idx < 6144) {
        int id = idx;
        int ct = id >> 11;
        int c = id & 2047;
        int gn = c >> 9, s = (c >> 6) & 7, h = (c >> 5) & 1, n = c & 31;
        int k0 = s * 16 + h * 8;
        int col = gn * 32 + n;
        const float* W = (ct == 0) ? W1root : (W1rel + (size_t)(ct - 1) * 16384);
#pragma unroll
        for (int j = 0; j < 8; j++) o[j] = f2bf(W[(k0 + j) * 128 + col]);
        Bpk1[id] = pack8(o);
    } else {
        int id = idx - 6144;
        int ct = id >> 11;
        int c = id & 2047;
        int gn = c >> 9, s = (c >> 6) & 7, h = (c >> 5) & 1, n = c & 31;
        int k0 = s * 16 + h * 8;
        int colg = ct * 128 + gn * 32 + n;
#pragma unroll
        for (int j = 0; j < 8; j++) {
            float f = 0.f;
            if (colg < 64)       f = W2root[(k0 + j) * 64 + colg];
            else if (colg < 128) f = W2rel[(k0 + j) * 64 + (colg - 64)];
            else if (colg < 192) f = W2rel[8192 + (k0 + j) * 64 + (colg - 128)];
            o[j] = f2bf(f);
        }
        Bpk2[id] = pack8(o);
    }
}

// ---------------- bf16 MFMA GEMM: Out[N x Ld] = A[N x 128] @ W ----------------
// Block: 256 thr = 4 waves (2x2), tile 128x128, full K=128 in LDS, 32x32x16 MFMA.
// A LDS frag-ordered: chunk c = g*512 + s*64 + h*32 + m  ->  A[g*32+m][s*16+h*8+j].
// Epilogue bounces through LDS for vectorized bf16 stores.

__global__ __launch_bounds__(256)
void k_gemm(const ushort* __restrict__ A, const ushort* __restrict__ Bpk,
            ushort* __restrict__ Out, int N, int Ld) {
    __shared__ ushort SH[32768];          // A:[0,16384) B:[16384,32768); C reuses A region
    ushort* Alds = SH;
    ushort* Blds = SH + 16384;

    const int tid = threadIdx.x;
    const int lane = tid & 63;
    const int w = tid >> 6;
    const int wm = w >> 1, wn = w & 1;
    const int rowBase = blockIdx.x * 128;
    const int ct = blockIdx.y;
    const int colBase = ct * 128;

    // stage B (already in LDS order -> fully contiguous, conflict-free)
    const uint4* Bsrc = (const uint4*)Bpk + (size_t)ct * 2048;
#pragma unroll
    for (int i = 0; i < 8; i++) {
        int c = tid + i * 256;
        ((uint4*)Blds)[c] = Bsrc[c];
    }
    // stage A: LDS-contiguous writes, 256B-strided global reads (L1-absorbed)
#pragma unroll
    for (int i = 0; i < 8; i++) {
        int c = tid + i * 256;
        int m = c & 31, h = (c >> 5) & 1, s = (c >> 6) & 7, g = c >> 9;
        int row = rowBase + g * 32 + m;
        if (row >= N) row = N - 1;
        int kc = s * 2 + h;
        uint4 v = *(const uint4*)(A + (size_t)row * 128 + kc * 8);
        ((uint4*)Alds)[c] = v;
    }
    __syncthreads();

    floatx16 acc[2][2] = {};
#pragma unroll
    for (int s = 0; s < 8; s++) {
        short8 a0 = *(const short8*)&Alds[(((wm * 2 + 0) * 8 + s) * 64 + lane) * 8];
        short8 a1 = *(const short8*)&Alds[(((wm * 2 + 1) * 8 + s) * 64 + lane) * 8];
        short8 b0 = *(const short8*)&Blds[(((wn * 2 + 0) * 8 + s) * 64 + lane) * 8];
        short8 b1 = *(const short8*)&Blds[(((wn * 2 + 1) * 8 + s) * 64 + lane) * 8];
        acc[0][0] = __builtin_amdgcn_mfma_f32_32x32x16_bf16(a0, b0, acc[0][0], 0, 0, 0);
        acc[0][1] = __builtin_amdgcn_mfma_f32_32x32x16_bf16(a0, b1, acc[0][1], 0, 0, 0);
        acc[1][0] = __builtin_amdgcn_mfma_f32_32x32x16_bf16(a1, b0, acc[1][0], 0, 0, 0);
        acc[1][1] = __builtin_amdgcn_mfma_f32_32x32x16_bf16(a1, b1, acc[1][1], 0, 0, 0);
    }
    __syncthreads();

    // epilogue: bf16 -> Clds[128][136], then vectorized global stores
    ushort* Clds = SH;
    const int qr = 4 * (lane >> 5);
    const int cl = lane & 31;
#pragma unroll
    for (int mt = 0; mt < 2; mt++)
#pragma unroll
        for (int nt = 0; nt < 2; nt++) {
#pragma unroll
            for (int reg = 0; reg < 16; reg++) {
                int rl = (reg & 3) + 8 * (reg >> 2) + qr;
                Clds[(wm * 64 + mt * 32 + rl) * 136 + wn * 64 + nt * 32 + cl] =
                    f2bf(acc[mt][nt][reg]);
            }
        }
    __syncthreads();

    int r = tid >> 1, half = tid & 1;
    int grow = rowBase + r;
    if (grow < N) {
#pragma unroll
        for (int k = 0; k < 8; k++) {
            int c0 = half * 64 + k * 8;
            int col = colBase + c0;
            if (col < Ld) {
                uint4 v = *(const uint4*)&Clds[r * 136 + c0];
                *(uint4*)(Out + (size_t)grow * Ld + col) = v;
            }
        }
    }
}

// ------- layer-1 fused: gather-mean of t1 msgs + root + bias + relu -> h bf16
// t1: [N x 384] bf16 = [N x 192] uints: cols(uint) 0..63 root, 64..127 rel0,
// 128..191 rel1. One wave per node, lane = channel pair.

__global__ void k_mid(const uint* __restrict__ T, const float* __restrict__ b1,
                      const int* __restrict__ offs, const int* __restrict__ esrc,
                      uint* __restrict__ hB, int N) {
    int wid = (int)((blockIdx.x * 256L + threadIdx.x) >> 6);
    int lane = threadIdx.x & 63;
    if (wid >= N) return;
    uint ru = T[(size_t)wid * 192 + lane];
    float2 bb = ((const float2*)b1)[lane];
    float vx = bflo(ru) + bb.x;
    float vy = bfhi(ru) + bb.y;
#pragma unroll
    for (int r = 0; r < 2; r++) {
        int segk = r * N + wid;
        int beg = (segk == 0) ? 0 : offs[segk - 1];
        int end = offs[segk];
        const uint* Y = T + 64 + r * 64 + lane;
        float ax = 0.f, ay = 0.f;
        int e = beg;
        for (; e + 4 <= end; e += 4) {
            int s0 = esrc[e], s1 = esrc[e + 1], s2 = esrc[e + 2], s3 = esrc[e + 3];
            uint u0 = Y[(size_t)s0 * 192];
            uint u1 = Y[(size_t)s1 * 192];
            uint u2 = Y[(size_t)s2 * 192];
            uint u3 = Y[(size_t)s3 * 192];
            ax += bflo(u0) + bflo(u1) + bflo(u2) + bflo(u3);
            ay += bfhi(u0) + bfhi(u1) + bfhi(u2) + bfhi(u3);
        }
        for (; e < end; e++) {
            uint u = Y[(size_t)esrc[e] * 192];
            ax += bflo(u);
            ay += bfhi(u);
        }
        float inv = 1.0f / fmaxf((float)(end - beg), 1.0f);
        vx += ax * inv;
        vy += ay * inv;
    }
    vx = fmaxf(vx, 0.f);
    vy = fmaxf(vy, 0.f);
    hB[(size_t)wid * 64 + lane] = (uint)f2bf(vx) | ((uint)f2bf(vy) << 16);
}

// ------- layer-2 fused: gather-mean of t2 msgs + root + bias + L2 norm -----
// t2: [N x 192] bf16: cols 0..63 root, 64..127 rel0, 128..191 rel1.

__global__ void k_final(const ushort* __restrict__ T2, const float* __restrict__ b2,
                        const int* __restrict__ offs, const int* __restrict__ esrc,
                        float* __restrict__ out, int N) {
    int wid = (int)((blockIdx.x * 256L + threadIdx.x) >> 6);
    int lane = threadIdx.x & 63;
    if (wid >= N) return;
    float v = bf1(T2[(size_t)wid * 192 + lane]) + b2[lane];
#pragma unroll
    for (int r = 0; r < 2; r++) {
        int segk = r * N + wid;
        int beg = (segk == 0) ? 0 : offs[segk - 1];
        int end = offs[segk];
        const ushort* Y = T2 + 64 + r * 64 + lane;
        float acc = 0.f;
        int e = beg;
        for (; e + 4 <= end; e += 4) {
            int s0 = esrc[e], s1 = esrc[e + 1], s2 = esrc[e + 2], s3 = esrc[e + 3];
            acc += bf1(Y[(size_t)s0 * 192]) + bf1(Y[(size_t)s1 * 192]) +
                   bf1(Y[(size_t)s2 * 192]) + bf1(Y[(size_t)s3 * 192]);
        }
        for (; e < end; e++) acc += bf1(Y[(size_t)esrc[e] * 192]);
        v += acc / fmaxf((float)(end - beg), 1.0f);
    }
    float sq = v * v;
#pragma unroll
    for (int o = 1; o < 64; o <<= 1) sq += __shfl_xor(sq, o, 64);
    float nrm = sqrtf(sq);
    out[(size_t)wid * OUT_CH + lane] = v / fmaxf(nrm, 1e-12f);
}

// ---------------- launch ----------------

extern "C" void kernel_launch(void* const* d_in, const int* in_sizes, int n_in,
                              void* d_out, int out_size, void* d_ws, size_t ws_size,
                              hipStream_t stream) {
    const float* x      = (const float*)d_in[0];
    const int*   ei     = (const int*)d_in[1];
    const int*   etype  = (const int*)d_in[2];
    const float* W1rel  = (const float*)d_in[3];  // [2,128,128]
    const float* W1root = (const float*)d_in[4];  // [128,128]
    const float* b1     = (const float*)d_in[5];
    const float* W2rel  = (const float*)d_in[6];  // [2,128,64]
    const float* W2root = (const float*)d_in[7];  // [128,64]
    const float* b2     = (const float*)d_in[8];
    float* out = (float*)d_out;

    const int N = in_sizes[0] / IN_CH;   // 100000
    const int E = in_sizes[2];           // 1600000
    const int NSEG = 2 * N;

    const int* src = ei;
    const int* dst = ei + E;

    char* base = (char*)d_ws;
    size_t off = 0;
    auto carve = [&](size_t bytes) -> void* {
        void* p = base + off;
        off = (off + bytes + 511) & ~(size_t)511;
        return p;
    };
    ushort* t1   = (ushort*)carve((size_t)N * 384 * sizeof(ushort)); // 76.8MB; t2 aliases
    ushort* xb   = (ushort*)carve((size_t)N * 128 * sizeof(ushort)); // 25.6MB; hB aliases
    int*    esrc = (int*)carve((size_t)E * sizeof(int));             // 6.4MB
    int*    deg  = (int*)carve((size_t)NSEG * sizeof(int));
    int*    offs = (int*)carve((size_t)(NSEG + 1) * sizeof(int));
    int     NB   = (NSEG + SCAN_CHUNK - 1) / SCAN_CHUNK;
    int*    bsums = (int*)carve((size_t)NB * sizeof(int));
    uint4*  Bpk1 = (uint4*)carve(6144 * sizeof(uint4));
    uint4*  Bpk2 = (uint4*)carve(4096 * sizeof(uint4));
    ushort* t2 = t1;        // t1 dead after k_mid
    ushort* hB = xb;        // xb dead after gemm1
    (void)ws_size; (void)n_in; (void)out_size;

    hipMemsetAsync(deg, 0, (size_t)NSEG * sizeof(int), stream);

    int eb = (E + 255) / 256;
    k_hist<<<eb, 256, 0, stream>>>(dst, etype, deg, E, N);
    k_scan_a<<<NB, 256, 0, stream>>>(deg, offs, bsums, NSEG);
    k_scan_b<<<1, 64, 0, stream>>>(bsums, offs, NB, NSEG);
    k_scan_c<<<(NSEG + 255) / 256, 256, 0, stream>>>(offs, bsums, NSEG);
    k_fill<<<eb, 256, 0, stream>>>(src, dst, etype, offs, esrc, E, N);

    int n8 = N * 128 / 8;
    k_cvt<<<(n8 + 255) / 256, 256, 0, stream>>>(x, (uint4*)xb, n8);
    k_prep<<<40, 256, 0, stream>>>(W1root, W1rel, W2root, W2rel, Bpk1, Bpk2);

    int rowTiles = (N + 127) / 128;
    int nodeBlocks = (int)(((long long)N * 64 + 255) / 256);

    // Layer 1: t1 = x @ [W1root|W1rel0|W1rel1], then fused agg+bias+relu -> h
    k_gemm<<<dim3(rowTiles, 3), 256, 0, stream>>>(xb, (const ushort*)Bpk1, t1, N, 384);
    k_mid<<<nodeBlocks, 256, 0, stream>>>((const uint*)t1, b1, offs, esrc, (uint*)hB, N);

    // Layer 2: t2 = h @ [W2root|W2rel0|W2rel1], then fused agg+bias+L2norm
    k_gemm<<<dim3(rowTiles, 2), 256, 0, stream>>>(hB, (const ushort*)Bpk2, t2, N, 192);
    k_final<<<nodeBlocks, 256, 0, stream>>>(t2, b2, offs, esrc, out, N);
}

// Round 4
// 399.660 us; speedup vs baseline: 2.1137x; 1.3506x over previous
//
#include <hip/hip_runtime.h>
#include <hip/hip_bf16.h>

// RGCN: 2-layer relational GCN + L2 normalize.
// R3: CSR build via 2-level radix partition (coalesced writes, no write-amp);
//     batch-8 clamped gathers in k_mid/k_final for MLP.

typedef unsigned int uint;
typedef unsigned short ushort;
typedef __attribute__((ext_vector_type(8))) short short8;
typedef __attribute__((ext_vector_type(16))) float floatx16;

#define IN_CH  128
#define OUT_CH 64
#define SCAN_CHUNK 2048
#define EPB 8192          // edges per partition block (256 thr x 32)
#define KPB 512           // keys per bucket
#define MAXBK 400         // LDS capacity for bucket counters

__device__ __forceinline__ ushort f2bf(float f) {
    uint u = __float_as_uint(f);
    u += 0x7FFF + ((u >> 16) & 1);
    return (ushort)(u >> 16);
}
__device__ __forceinline__ float bflo(uint u) { return __uint_as_float(u << 16); }
__device__ __forceinline__ float bfhi(uint u) { return __uint_as_float(u & 0xFFFF0000u); }
__device__ __forceinline__ float bf1(ushort s) { return __uint_as_float(((uint)s) << 16); }

// ---------------- radix CSR build ----------------
// key = et*N + dst in [0, 2N); bucket = key >> 9.

__global__ void k_count(const int* __restrict__ dst, const int* __restrict__ et,
                        int* __restrict__ cntblk, int E, int N, int NBK, int NBLK) {
    __shared__ int cnt[MAXBK];
    int tid = threadIdx.x, blk = blockIdx.x;
    for (int b = tid; b < NBK; b += 256) cnt[b] = 0;
    __syncthreads();
    int base = blk * EPB;
#pragma unroll 4
    for (int i = 0; i < EPB / 256; i++) {
        int e = base + i * 256 + tid;
        if (e < E) {
            int key = et[e] * N + dst[e];
            atomicAdd(&cnt[key >> 9], 1);
        }
    }
    __syncthreads();
    for (int b = tid; b < NBK; b += 256) cntblk[b * NBLK + blk] = cnt[b];
}

__global__ void k_scan_a(const int* __restrict__ deg, int* __restrict__ offs,
                         int* __restrict__ bsums, int n) {
    __shared__ int sdata[256];
    int b = blockIdx.x, t = threadIdx.x;
    int base = b * SCAN_CHUNK + t * 8;
    int v[8];
    int sum = 0;
#pragma unroll
    for (int i = 0; i < 8; i++) {
        int idx = base + i;
        int x = (idx < n) ? deg[idx] : 0;
        v[i] = sum;
        sum += x;
    }
    sdata[t] = sum;
    __syncthreads();
    for (int ofs = 1; ofs < 256; ofs <<= 1) {
        int val = sdata[t];
        int add = (t >= ofs) ? sdata[t - ofs] : 0;
        __syncthreads();
        sdata[t] = val + add;
        __syncthreads();
    }
    int texcl = (t == 0) ? 0 : sdata[t - 1];
    if (t == 255) bsums[b] = sdata[255];
#pragma unroll
    for (int i = 0; i < 8; i++) {
        int idx = base + i;
        if (idx < n) offs[idx] = texcl + v[i];
    }
}

__global__ void k_scan_b(int* __restrict__ bsums, int* __restrict__ offs, int nb, int n) {
    if (blockIdx.x == 0 && threadIdx.x == 0) {
        int run = 0;
        for (int b = 0; b < nb; b++) {
            int t = bsums[b];
            bsums[b] = run;
            run += t;
        }
        offs[n] = run;
    }
}

__global__ void k_scan_c(int* __restrict__ offs, const int* __restrict__ bsums, int n) {
    int i = blockIdx.x * blockDim.x + threadIdx.x;
    if (i < n) offs[i] += bsums[i / SCAN_CHUNK];
}

// partition: write (src,key) pairs bucket-contiguously using exact per-
// (bucket,block) bases from the flattened scan. No global atomics.
__global__ void k_part(const int* __restrict__ src, const int* __restrict__ dst,
                       const int* __restrict__ et, const int* __restrict__ basebb,
                       uint2* __restrict__ stage, int E, int N, int NBK, int NBLK) {
    __shared__ int cnt[MAXBK];
    __shared__ int basel[MAXBK];
    int tid = threadIdx.x, blk = blockIdx.x;
    for (int b = tid; b < NBK; b += 256) {
        cnt[b] = 0;
        basel[b] = basebb[b * NBLK + blk];
    }
    __syncthreads();
    int base = blk * EPB;
#pragma unroll 4
    for (int i = 0; i < EPB / 256; i++) {
        int e = base + i * 256 + tid;
        if (e < E) {
            int s = src[e];
            int key = et[e] * N + dst[e];
            int bk = key >> 9;
            int r = atomicAdd(&cnt[bk], 1);
            stage[basel[bk] + r] = make_uint2((uint)s, (uint)key);
        }
    }
}

// fine sort within bucket: LDS 512-key histogram + scan -> offs (ends) +
// esrc scatter confined to a ~16KB L2-resident region.
__global__ void k_fine(const uint2* __restrict__ stage, const int* __restrict__ basebb,
                       int* __restrict__ offs, int* __restrict__ esrc,
                       int E, int NBK, int NBLK) {
    __shared__ int kcnt[KPB];
    __shared__ int kexc[KPB];
    __shared__ int ssum[256];
    int tid = threadIdx.x, b = blockIdx.x;
    int start = basebb[b * NBLK];
    int endB = (b == NBK - 1) ? E : basebb[(b + 1) * NBLK];
    int size = endB - start;

    kcnt[tid] = 0;
    kcnt[tid + 256] = 0;
    __syncthreads();
    for (int i = tid; i < size; i += 256) {
        uint2 p = stage[start + i];
        atomicAdd(&kcnt[(int)p.y - (b << 9)], 1);
    }
    __syncthreads();
    int v0 = kcnt[2 * tid], v1 = kcnt[2 * tid + 1];
    ssum[tid] = v0 + v1;
    __syncthreads();
    for (int ofs = 1; ofs < 256; ofs <<= 1) {
        int val = ssum[tid];
        int add = (tid >= ofs) ? ssum[tid - ofs] : 0;
        __syncthreads();
        ssum[tid] = val + add;
        __syncthreads();
    }
    int texcl = (tid == 0) ? 0 : ssum[tid - 1];
    kexc[2 * tid] = texcl;
    kexc[2 * tid + 1] = texcl + v0;
    int gb = b << 9;
    offs[gb + 2 * tid] = start + texcl + v0;
    offs[gb + 2 * tid + 1] = start + texcl + v0 + v1;
    __syncthreads();
    for (int i = tid; i < size; i += 256) {
        uint2 p = stage[start + i];
        int r = atomicAdd(&kexc[(int)p.y - (b << 9)], 1);
        esrc[start + r] = (int)p.x;
    }
}

// ---------------- fp32 -> bf16 conversion of x ----------------

__global__ void k_cvt(const float* __restrict__ x, uint4* __restrict__ xb, int n8) {
    int i = blockIdx.x * 256 + threadIdx.x;
    if (i >= n8) return;
    const float4 f0 = ((const float4*)x)[(size_t)i * 2];
    const float4 f1 = ((const float4*)x)[(size_t)i * 2 + 1];
    uint4 o;
    o.x = (uint)f2bf(f0.x) | ((uint)f2bf(f0.y) << 16);
    o.y = (uint)f2bf(f0.z) | ((uint)f2bf(f0.w) << 16);
    o.z = (uint)f2bf(f1.x) | ((uint)f2bf(f1.y) << 16);
    o.w = (uint)f2bf(f1.z) | ((uint)f2bf(f1.w) << 16);
    xb[i] = o;
}

// ------------- weight pre-pack into MFMA-B fragment order (bf16) -----------

__device__ __forceinline__ uint4 pack8(const ushort* o) {
    uint4 v;
    v.x = (uint)o[0] | ((uint)o[1] << 16);
    v.y = (uint)o[2] | ((uint)o[3] << 16);
    v.z = (uint)o[4] | ((uint)o[5] << 16);
    v.w = (uint)o[6] | ((uint)o[7] << 16);
    return v;
}

__global__ void k_prep(const float* __restrict__ W1root, const float* __restrict__ W1rel,
                       const float* __restrict__ W2root, const float* __restrict__ W2rel,
                       uint4* __restrict__ Bpk1, uint4* __restrict__ Bpk2) {
    int idx = blockIdx.x * 256 + threadIdx.x;
    if (idx >= 10240) return;
    ushort o[8];
    if (idx < 6144) {
        int id = idx;
        int ct = id >> 11;
        int c = id & 2047;
        int gn = c >> 9, s = (c >> 6) & 7, h = (c >> 5) & 1, n = c & 31;
        int k0 = s * 16 + h * 8;
        int col = gn * 32 + n;
        const float* W = (ct == 0) ? W1root : (W1rel + (size_t)(ct - 1) * 16384);
#pragma unroll
        for (int j = 0; j < 8; j++) o[j] = f2bf(W[(k0 + j) * 128 + col]);
        Bpk1[id] = pack8(o);
    } else {
        int id = idx - 6144;
        int ct = id >> 11;
        int c = id & 2047;
        int gn = c >> 9, s = (c >> 6) & 7, h = (c >> 5) & 1, n = c & 31;
        int k0 = s * 16 + h * 8;
        int colg = ct * 128 + gn * 32 + n;
#pragma unroll
        for (int j = 0; j < 8; j++) {
            float f = 0.f;
            if (colg < 64)       f = W2root[(k0 + j) * 64 + colg];
            else if (colg < 128) f = W2rel[(k0 + j) * 64 + (colg - 64)];
            else if (colg < 192) f = W2rel[8192 + (k0 + j) * 64 + (colg - 128)];
            o[j] = f2bf(f);
        }
        Bpk2[id] = pack8(o);
    }
}

// ---------------- bf16 MFMA GEMM (unchanged from R2) ----------------

__global__ __launch_bounds__(256)
void k_gemm(const ushort* __restrict__ A, const ushort* __restrict__ Bpk,
            ushort* __restrict__ Out, int N, int Ld) {
    __shared__ ushort SH[32768];
    ushort* Alds = SH;
    ushort* Blds = SH + 16384;

    const int tid = threadIdx.x;
    const int lane = tid & 63;
    const int w = tid >> 6;
    const int wm = w >> 1, wn = w & 1;
    const int rowBase = blockIdx.x * 128;
    const int ct = blockIdx.y;
    const int colBase = ct * 128;

    const uint4* Bsrc = (const uint4*)Bpk + (size_t)ct * 2048;
#pragma unroll
    for (int i = 0; i < 8; i++) {
        int c = tid + i * 256;
        ((uint4*)Blds)[c] = Bsrc[c];
    }
#pragma unroll
    for (int i = 0; i < 8; i++) {
        int c = tid + i * 256;
        int m = c & 31, h = (c >> 5) & 1, s = (c >> 6) & 7, g = c >> 9;
        int row = rowBase + g * 32 + m;
        if (row >= N) row = N - 1;
        int kc = s * 2 + h;
        uint4 v = *(const uint4*)(A + (size_t)row * 128 + kc * 8);
        ((uint4*)Alds)[c] = v;
    }
    __syncthreads();

    floatx16 acc[2][2] = {};
#pragma unroll
    for (int s = 0; s < 8; s++) {
        short8 a0 = *(const short8*)&Alds[(((wm * 2 + 0) * 8 + s) * 64 + lane) * 8];
        short8 a1 = *(const short8*)&Alds[(((wm * 2 + 1) * 8 + s) * 64 + lane) * 8];
        short8 b0 = *(const short8*)&Blds[(((wn * 2 + 0) * 8 + s) * 64 + lane) * 8];
        short8 b1 = *(const short8*)&Blds[(((wn * 2 + 1) * 8 + s) * 64 + lane) * 8];
        acc[0][0] = __builtin_amdgcn_mfma_f32_32x32x16_bf16(a0, b0, acc[0][0], 0, 0, 0);
        acc[0][1] = __builtin_amdgcn_mfma_f32_32x32x16_bf16(a0, b1, acc[0][1], 0, 0, 0);
        acc[1][0] = __builtin_amdgcn_mfma_f32_32x32x16_bf16(a1, b0, acc[1][0], 0, 0, 0);
        acc[1][1] = __builtin_amdgcn_mfma_f32_32x32x16_bf16(a1, b1, acc[1][1], 0, 0, 0);
    }
    __syncthreads();

    ushort* Clds = SH;
    const int qr = 4 * (lane >> 5);
    const int cl = lane & 31;
#pragma unroll
    for (int mt = 0; mt < 2; mt++)
#pragma unroll
        for (int nt = 0; nt < 2; nt++) {
#pragma unroll
            for (int reg = 0; reg < 16; reg++) {
                int rl = (reg & 3) + 8 * (reg >> 2) + qr;
                Clds[(wm * 64 + mt * 32 + rl) * 136 + wn * 64 + nt * 32 + cl] =
                    f2bf(acc[mt][nt][reg]);
            }
        }
    __syncthreads();

    int r = tid >> 1, half = tid & 1;
    int grow = rowBase + r;
    if (grow < N) {
#pragma unroll
        for (int k = 0; k < 8; k++) {
            int c0 = half * 64 + k * 8;
            int col = colBase + c0;
            if (col < Ld) {
                uint4 v = *(const uint4*)&Clds[r * 136 + c0];
                *(uint4*)(Out + (size_t)grow * Ld + col) = v;
            }
        }
    }
}

// ------- layer-1 fused: gather-mean + root + bias + relu -> h bf16 ---------
// Batch-8 clamped gather: always 8 row loads in flight; clamped dups are L1 hits.

__global__ void k_mid(const uint* __restrict__ T, const float* __restrict__ b1,
                      const int* __restrict__ offs, const int* __restrict__ esrc,
                      uint* __restrict__ hB, int N) {
    int wid = (int)((blockIdx.x * 256L + threadIdx.x) >> 6);
    int lane = threadIdx.x & 63;
    if (wid >= N) return;
    uint ru = T[(size_t)wid * 192 + lane];
    float2 bb = ((const float2*)b1)[lane];
    float vx = bflo(ru) + bb.x;
    float vy = bfhi(ru) + bb.y;
#pragma unroll
    for (int r = 0; r < 2; r++) {
        int segk = r * N + wid;
        int beg = (segk == 0) ? 0 : offs[segk - 1];
        int end = offs[segk];
        if (end > beg) {
            const uint* Y = T + 64 + r * 64 + lane;
            int lim = end - 1;
            float ax = 0.f, ay = 0.f;
            for (int eb = beg; eb < end; eb += 8) {
                int id[8];
                uint u[8];
#pragma unroll
                for (int k = 0; k < 8; k++) {
                    int ee = eb + k;
                    id[k] = esrc[ee <= lim ? ee : lim];
                }
#pragma unroll
                for (int k = 0; k < 8; k++) u[k] = Y[(size_t)id[k] * 192];
#pragma unroll
                for (int k = 0; k < 8; k++) {
                    if (eb + k <= lim) {   // wave-uniform
                        ax += bflo(u[k]);
                        ay += bfhi(u[k]);
                    }
                }
            }
            float inv = 1.0f / (float)(end - beg);
            vx += ax * inv;
            vy += ay * inv;
        }
    }
    vx = fmaxf(vx, 0.f);
    vy = fmaxf(vy, 0.f);
    hB[(size_t)wid * 64 + lane] = (uint)f2bf(vx) | ((uint)f2bf(vy) << 16);
}

// ------- layer-2 fused: gather-mean + root + bias + L2 norm ----------------

__global__ void k_final(const ushort* __restrict__ T2, const float* __restrict__ b2,
                        const int* __restrict__ offs, const int* __restrict__ esrc,
                        float* __restrict__ out, int N) {
    int wid = (int)((blockIdx.x * 256L + threadIdx.x) >> 6);
    int lane = threadIdx.x & 63;
    if (wid >= N) return;
    float v = bf1(T2[(size_t)wid * 192 + lane]) + b2[lane];
#pragma unroll
    for (int r = 0; r < 2; r++) {
        int segk = r * N + wid;
        int beg = (segk == 0) ? 0 : offs[segk - 1];
        int end = offs[segk];
        if (end > beg) {
            const ushort* Y = T2 + 64 + r * 64 + lane;
            int lim = end - 1;
            float acc = 0.f;
            for (int eb = beg; eb < end; eb += 8) {
                int id[8];
                ushort u[8];
#pragma unroll
                for (int k = 0; k < 8; k++) {
                    int ee = eb + k;
                    id[k] = esrc[ee <= lim ? ee : lim];
                }
#pragma unroll
                for (int k = 0; k < 8; k++) u[k] = Y[(size_t)id[k] * 192];
#pragma unroll
                for (int k = 0; k < 8; k++) {
                    if (eb + k <= lim) acc += bf1(u[k]);
                }
            }
            v += acc / (float)(end - beg);
        }
    }
    float sq = v * v;
#pragma unroll
    for (int o = 1; o < 64; o <<= 1) sq += __shfl_xor(sq, o, 64);
    float nrm = sqrtf(sq);
    out[(size_t)wid * OUT_CH + lane] = v / fmaxf(nrm, 1e-12f);
}

// ---------------- launch ----------------

extern "C" void kernel_launch(void* const* d_in, const int* in_sizes, int n_in,
                              void* d_out, int out_size, void* d_ws, size_t ws_size,
                              hipStream_t stream) {
    const float* x      = (const float*)d_in[0];
    const int*   ei     = (const int*)d_in[1];
    const int*   etype  = (const int*)d_in[2];
    const float* W1rel  = (const float*)d_in[3];
    const float* W1root = (const float*)d_in[4];
    const float* b1     = (const float*)d_in[5];
    const float* W2rel  = (const float*)d_in[6];
    const float* W2root = (const float*)d_in[7];
    const float* b2     = (const float*)d_in[8];
    float* out = (float*)d_out;

    const int N = in_sizes[0] / IN_CH;   // 100000
    const int E = in_sizes[2];           // 1600000
    const int NKEY = 2 * N;
    const int NBK  = (NKEY + KPB - 1) / KPB;       // 391 buckets
    const int NBLK = (E + EPB - 1) / EPB;          // 196 partition blocks
    const int NSC  = NBK * NBLK;                   // flattened count array

    const int* src = ei;
    const int* dst = ei + E;

    char* base = (char*)d_ws;
    size_t off = 0;
    auto carve = [&](size_t bytes) -> void* {
        void* p = base + off;
        off = (off + bytes + 511) & ~(size_t)511;
        return p;
    };
    ushort* t1    = (ushort*)carve((size_t)N * 384 * sizeof(ushort)); // 76.8MB
    ushort* xb    = (ushort*)carve((size_t)N * 128 * sizeof(ushort)); // 25.6MB
    int*    esrc  = (int*)carve((size_t)E * sizeof(int));             // 6.4MB
    uint2*  stage = (uint2*)carve((size_t)E * sizeof(uint2));         // 12.8MB
    int*    offs  = (int*)carve((size_t)NBK * KPB * sizeof(int));     // 0.8MB
    int*    cntblk= (int*)carve((size_t)NSC * sizeof(int));
    int*    basebb= (int*)carve((size_t)(NSC + 1) * sizeof(int));
    int     NB    = (NSC + SCAN_CHUNK - 1) / SCAN_CHUNK;
    int*    bsums = (int*)carve((size_t)NB * sizeof(int));
    uint4*  Bpk1  = (uint4*)carve(6144 * sizeof(uint4));
    uint4*  Bpk2  = (uint4*)carve(4096 * sizeof(uint4));
    ushort* t2 = t1;
    ushort* hB = xb;
    (void)ws_size; (void)n_in; (void)out_size;

    // CSR build: count -> scan -> partition -> fine sort
    k_count<<<NBLK, 256, 0, stream>>>(dst, etype, cntblk, E, N, NBK, NBLK);
    k_scan_a<<<NB, 256, 0, stream>>>(cntblk, basebb, bsums, NSC);
    k_scan_b<<<1, 64, 0, stream>>>(bsums, basebb, NB, NSC);
    k_scan_c<<<(NSC + 255) / 256, 256, 0, stream>>>(basebb, bsums, NSC);
    k_part<<<NBLK, 256, 0, stream>>>(src, dst, etype, basebb, stage, E, N, NBK, NBLK);
    k_fine<<<NBK, 256, 0, stream>>>(stage, basebb, offs, esrc, E, NBK, NBLK);

    int n8 = N * 128 / 8;
    k_cvt<<<(n8 + 255) / 256, 256, 0, stream>>>(x, (uint4*)xb, n8);
    k_prep<<<40, 256, 0, stream>>>(W1root, W1rel, W2root, W2rel, Bpk1, Bpk2);

    int rowTiles = (N + 127) / 128;
    int nodeBlocks = (int)(((long long)N * 64 + 255) / 256);

    k_gemm<<<dim3(rowTiles, 3), 256, 0, stream>>>(xb, (const ushort*)Bpk1, t1, N, 384);
    k_mid<<<nodeBlocks, 256, 0, stream>>>((const uint*)t1, b1, offs, esrc, (uint*)hB, N);

    k_gemm<<<dim3(rowTiles, 2), 256, 0, stream>>>(hB, (const ushort*)Bpk2, t2, N, 192);
    k_final<<<nodeBlocks, 256, 0, stream>>>(t2, b2, offs, esrc, out, N);
}